// Round 1
// baseline (165.645 us; speedup 1.0000x reference)
//
#include <hip/hip_runtime.h>
#include <math.h>

#define NQ        14
#define DIM       16384      // 2^14
#define BATCHN    128
#define NGATES    13
#define NGEN      15
#define NOBSN     13
#define DEPTHN    4
#define INDIM     256
#define HIDDIM    256
#define ENCDIM    195
#define TCIRC     1024

// Pauli 2x2 matrices (real, imag parts). Order: I, X, Y, Z.
__constant__ float c_PR[4][2][2] = {
  {{1.f, 0.f}, {0.f, 1.f}},   // I
  {{0.f, 1.f}, {1.f, 0.f}},   // X
  {{0.f, 0.f}, {0.f, 0.f}},   // Y (real part)
  {{1.f, 0.f}, {0.f,-1.f}},   // Z
};
__constant__ float c_PI[4][2][2] = {
  {{0.f, 0.f}, {0.f, 0.f}},
  {{0.f, 0.f}, {0.f, 0.f}},
  {{0.f,-1.f}, {1.f, 0.f}},   // Y (imag part)
  {{0.f, 0.f}, {0.f, 0.f}},
};

// ---------------- encoder: enc = silu(x W1^T + b1) W2^T + b2 ----------------
__global__ void encoder_kernel(const float* __restrict__ x,
                               const float* __restrict__ W1,
                               const float* __restrict__ b1,
                               const float* __restrict__ W2,
                               const float* __restrict__ b2,
                               float* __restrict__ enc) {
  __shared__ float xrow[INDIM];
  __shared__ float hrow[HIDDIM];
  const int b = blockIdx.x, t = threadIdx.x;
  xrow[t] = x[b * INDIM + t];
  __syncthreads();
  float acc = b1[t];
  const float* w = W1 + t * INDIM;
  for (int k = 0; k < INDIM; ++k) acc = fmaf(w[k], xrow[k], acc);
  hrow[t] = acc / (1.f + expf(-acc));       // silu
  __syncthreads();
  if (t < ENCDIM) {
    float a2 = b2[t];
    const float* w2 = W2 + t * HIDDIM;
    for (int k = 0; k < HIDDIM; ++k) a2 = fmaf(w2[k], hrow[k], a2);
    enc[b * ENCDIM + t] = a2;
  }
}

// ---------------- build U = exp(i * sum_g theta_g G_g), one thread each -----
__global__ void build_u_kernel(const float* __restrict__ enc,
                               float2* __restrict__ Umats) {
  const int idx = blockIdx.x * blockDim.x + threadIdx.x;
  if (idx >= BATCHN * NGATES) return;
  const int b = idx / NGATES, g = idx % NGATES;
  const float* th = enc + b * ENCDIM + g * NGEN;

  // A = sum theta_g kron(P_a, P_b), (a,b) = pair index g+1
  float Ar[16], Ai[16];
  for (int i = 0; i < 16; ++i) { Ar[i] = 0.f; Ai[i] = 0.f; }
  for (int t = 0; t < NGEN; ++t) {
    const int p = t + 1;
    const int pa = p >> 2, pb = p & 3;
    const float theta = th[t];
    for (int i = 0; i < 4; ++i)
      for (int j = 0; j < 4; ++j) {
        const float ar = c_PR[pa][i >> 1][j >> 1], ai = c_PI[pa][i >> 1][j >> 1];
        const float br = c_PR[pb][i & 1][j & 1],  bi = c_PI[pb][i & 1][j & 1];
        Ar[i * 4 + j] = fmaf(theta, ar * br - ai * bi, Ar[i * 4 + j]);
        Ai[i * 4 + j] = fmaf(theta, ar * bi + ai * br, Ai[i * 4 + j]);
      }
  }

  // infinity norm of A
  float nrm = 0.f;
  for (int i = 0; i < 4; ++i) {
    float rs = 0.f;
    for (int j = 0; j < 4; ++j)
      rs += sqrtf(Ar[i * 4 + j] * Ar[i * 4 + j] + Ai[i * 4 + j] * Ai[i * 4 + j]);
    nrm = fmaxf(nrm, rs);
  }
  // scaling: M = iA / 2^s with ||M|| <= 0.4
  int sct = 0;
  float scale = 1.f;
  while (nrm * scale > 0.4f && sct < 30) { scale *= 0.5f; ++sct; }

  float Mr[16], Mi[16];
  for (int i = 0; i < 16; ++i) { Mr[i] = -Ai[i] * scale; Mi[i] = Ar[i] * scale; }

  // Taylor via Horner: R = I; for k=K..1: R = I + (M R)/k
  float Rr[16], Ri[16];
  for (int i = 0; i < 16; ++i) { Rr[i] = (i % 5 == 0) ? 1.f : 0.f; Ri[i] = 0.f; }
  for (int k = 12; k >= 1; --k) {
    float Tr[16], Ti[16];
    const float inv = 1.f / (float)k;
    for (int i = 0; i < 4; ++i)
      for (int j = 0; j < 4; ++j) {
        float tr = 0.f, ti = 0.f;
        for (int l = 0; l < 4; ++l) {
          const float mr = Mr[i * 4 + l], mi = Mi[i * 4 + l];
          const float rr = Rr[l * 4 + j], ri = Ri[l * 4 + j];
          tr += mr * rr - mi * ri;
          ti += mr * ri + mi * rr;
        }
        Tr[i * 4 + j] = ((i == j) ? 1.f : 0.f) + inv * tr;
        Ti[i * 4 + j] = inv * ti;
      }
    for (int i = 0; i < 16; ++i) { Rr[i] = Tr[i]; Ri[i] = Ti[i]; }
  }
  // squarings
  for (int it = 0; it < sct; ++it) {
    float Tr[16], Ti[16];
    for (int i = 0; i < 4; ++i)
      for (int j = 0; j < 4; ++j) {
        float tr = 0.f, ti = 0.f;
        for (int l = 0; l < 4; ++l) {
          const float ar = Rr[i * 4 + l], ai = Ri[i * 4 + l];
          const float br = Rr[l * 4 + j], bi = Ri[l * 4 + j];
          tr += ar * br - ai * bi;
          ti += ar * bi + ai * br;
        }
        Tr[i * 4 + j] = tr; Ti[i * 4 + j] = ti;
      }
    for (int i = 0; i < 16; ++i) { Rr[i] = Tr[i]; Ri[i] = Ti[i]; }
  }
  for (int i = 0; i < 16; ++i)
    Umats[idx * 16 + i] = make_float2(Rr[i], Ri[i]);
}

// ---------------- full circuit: one block per batch element, state in LDS ---
__launch_bounds__(TCIRC, 1)
__global__ void circuit_kernel(const float2* __restrict__ Umats,
                               const float* __restrict__ vp,
                               const float* __restrict__ oA,
                               const float* __restrict__ oB,
                               const float* __restrict__ oD,
                               float* __restrict__ out) {
  __shared__ float2 st[DIM];            // 128 KiB state
  __shared__ float2 Ush[NGATES * 16];
  __shared__ float2 Hsh[NOBSN * 16];
  __shared__ float  ryc[DEPTHN * NQ];
  __shared__ float  rys[DEPTHN * NQ];
  __shared__ float  red[TCIRC / 64];

  const int b = blockIdx.x;
  const int tid = threadIdx.x;

  for (int i = tid; i < NGATES * 16; i += TCIRC)
    Ush[i] = Umats[b * NGATES * 16 + i];
  for (int i = tid; i < DEPTHN * NQ; i += TCIRC) {
    const float h = 0.5f * vp[i];
    ryc[i] = cosf(h);
    rys[i] = sinf(h);
  }
  if (tid < NOBSN) {
    const int rr[6] = {1, 2, 2, 3, 3, 3};
    const int cc[6] = {0, 0, 1, 0, 1, 2};
    float2 H[16];
    #pragma unroll
    for (int i = 0; i < 16; ++i) H[i] = make_float2(0.f, 0.f);
    for (int m = 0; m < 6; ++m) {
      const float a = oA[tid * 6 + m], bb = oB[tid * 6 + m];
      H[rr[m] * 4 + cc[m]] = make_float2(a, bb);
      H[cc[m] * 4 + rr[m]] = make_float2(a, -bb);
    }
    H[0]  = make_float2(2.f * oD[tid * 4 + 1], 0.f);
    H[5]  = make_float2(2.f * oD[tid * 4 + 2], 0.f);
    H[10] = make_float2(2.f * oD[tid * 4 + 3], 0.f);
    for (int i = 0; i < 16; ++i) Hsh[tid * 16 + i] = H[i];
  }
  for (int y = tid; y < DIM; y += TCIRC)
    st[y] = make_float2(y == 0 ? 1.f : 0.f, 0.f);
  __syncthreads();

  // ---- SU(4) brick-layer encoding gates ----
  const int starts[NGATES] = {0, 2, 4, 6, 8, 10, 12, 1, 3, 5, 7, 9, 11};
  for (int g = 0; g < NGATES; ++g) {
    const int q = starts[g];
    const int sh = 12 - q;
    const int mask = (1 << sh) - 1;
    float2 u[16];
    #pragma unroll
    for (int i = 0; i < 16; ++i) u[i] = Ush[g * 16 + i];
    for (int G = tid; G < DIM / 4; G += TCIRC) {
      const int base = ((G & ~mask) << 2) | (G & mask);
      float2 xv[4];
      #pragma unroll
      for (int k = 0; k < 4; ++k) xv[k] = st[base + (k << sh)];
      #pragma unroll
      for (int k = 0; k < 4; ++k) {
        float2 acc = make_float2(0.f, 0.f);
        #pragma unroll
        for (int l = 0; l < 4; ++l) {
          const float2 uu = u[k * 4 + l];
          acc.x = fmaf(uu.x, xv[l].x, fmaf(-uu.y, xv[l].y, acc.x));
          acc.y = fmaf(uu.x, xv[l].y, fmaf(uu.y, xv[l].x, acc.y));
        }
        st[base + (k << sh)] = acc;
      }
    }
    __syncthreads();
  }

  // ---- variational ansatz: RY layer (fused pairs) + CNOT chain (one perm) --
  for (int d = 0; d < DEPTHN; ++d) {
    for (int pq = 0; pq < NQ / 2; ++pq) {
      const int q = 2 * pq;
      const int sh = 12 - q;
      const int mask = (1 << sh) - 1;
      const float c0 = ryc[d * NQ + q],     s0 = rys[d * NQ + q];
      const float c1 = ryc[d * NQ + q + 1], s1 = rys[d * NQ + q + 1];
      const float K[16] = { c0*c1, -c0*s1, -s0*c1,  s0*s1,
                            c0*s1,  c0*c1, -s0*s1, -s0*c1,
                            s0*c1, -s0*s1,  c0*c1, -c0*s1,
                            s0*s1,  s0*c1,  c0*s1,  c0*c1 };
      for (int G = tid; G < DIM / 4; G += TCIRC) {
        const int base = ((G & ~mask) << 2) | (G & mask);
        float2 xv[4];
        #pragma unroll
        for (int k = 0; k < 4; ++k) xv[k] = st[base + (k << sh)];
        #pragma unroll
        for (int k = 0; k < 4; ++k) {
          float rx = K[k*4+0] * xv[0].x;
          float ry_ = K[k*4+0] * xv[0].y;
          #pragma unroll
          for (int l = 1; l < 4; ++l) {
            rx  = fmaf(K[k*4+l], xv[l].x, rx);
            ry_ = fmaf(K[k*4+l], xv[l].y, ry_);
          }
          st[base + (k << sh)] = make_float2(rx, ry_);
        }
      }
      __syncthreads();
    }
    // CNOT chain q=0..12 collapsed into one permutation:
    // new[y] = old[sigma_0(sigma_1(...sigma_12(y)))],
    // sigma_q: flip bit (12-q) if bit (13-q) set.
    float2 vals[DIM / TCIRC];
    #pragma unroll
    for (int i = 0; i < DIM / TCIRC; ++i) {
      int t = tid + i * TCIRC;
      #pragma unroll
      for (int q = 12; q >= 0; --q)
        t ^= ((t >> (13 - q)) & 1) << (12 - q);
      vals[i] = st[t];
    }
    __syncthreads();
    #pragma unroll
    for (int i = 0; i < DIM / TCIRC; ++i)
      st[tid + i * TCIRC] = vals[i];
    __syncthreads();
  }

  // ---- expectation values ----
  for (int o = 0; o < NOBSN; ++o) {
    const int sh = 12 - o;
    const int mask = (1 << sh) - 1;
    float2 h[16];
    #pragma unroll
    for (int i = 0; i < 16; ++i) h[i] = Hsh[o * 16 + i];
    float acc = 0.f;
    for (int G = tid; G < DIM / 4; G += TCIRC) {
      const int base = ((G & ~mask) << 2) | (G & mask);
      float2 xv[4];
      #pragma unroll
      for (int k = 0; k < 4; ++k) xv[k] = st[base + (k << sh)];
      #pragma unroll
      for (int k = 0; k < 4; ++k) {
        #pragma unroll
        for (int l = 0; l < 4; ++l) {
          const float2 hh = h[k * 4 + l];
          const float wr = hh.x * xv[l].x - hh.y * xv[l].y;
          const float wi = hh.x * xv[l].y + hh.y * xv[l].x;
          acc += xv[k].x * wr + xv[k].y * wi;
        }
      }
    }
    #pragma unroll
    for (int off = 32; off > 0; off >>= 1)
      acc += __shfl_down(acc, off, 64);
    const int lane = tid & 63, wid = tid >> 6;
    if (lane == 0) red[wid] = acc;
    __syncthreads();
    if (tid == 0) {
      float s = 0.f;
      for (int w = 0; w < TCIRC / 64; ++w) s += red[w];
      out[b * NOBSN + o] = s;
    }
    __syncthreads();
  }
}

extern "C" void kernel_launch(void* const* d_in, const int* in_sizes, int n_in,
                              void* d_out, int out_size, void* d_ws, size_t ws_size,
                              hipStream_t stream) {
  const float* x  = (const float*)d_in[0];
  const float* W1 = (const float*)d_in[1];
  const float* b1 = (const float*)d_in[2];
  const float* W2 = (const float*)d_in[3];
  const float* b2 = (const float*)d_in[4];
  const float* vp = (const float*)d_in[5];
  const float* oA = (const float*)d_in[6];
  const float* oB = (const float*)d_in[7];
  const float* oD = (const float*)d_in[8];
  float* out = (float*)d_out;

  float* enc = (float*)d_ws;
  const size_t enc_bytes = (size_t)BATCHN * ENCDIM * sizeof(float);
  float2* U = (float2*)((char*)d_ws + ((enc_bytes + 255) & ~(size_t)255));

  encoder_kernel<<<BATCHN, 256, 0, stream>>>(x, W1, b1, W2, b2, enc);
  build_u_kernel<<<(BATCHN * NGATES + 255) / 256, 256, 0, stream>>>(enc, U);
  circuit_kernel<<<BATCHN, TCIRC, 0, stream>>>(U, vp, oA, oB, oD, out);
}